// Round 5
// baseline (960.553 us; speedup 1.0000x reference)
//
#include <hip/hip_runtime.h>

#define NTHREADS 256
#define HID 96
#define INF 64
#define OUTF 16
#define NLAYERS 16
#define NHW 25088     // packed histogram words (2 nodes/word), fits n<=50176
#define CB 64         // histogram blocks

typedef __attribute__((ext_vector_type(8))) unsigned short ushort8_t;
typedef __attribute__((ext_vector_type(8))) short short8_t;   // MFMA bf16 A/B frag
typedef __attribute__((ext_vector_type(4))) float f32x4_t;    // MFMA C/D frag

static __device__ __forceinline__ float bf2f(unsigned short u) {
  return __uint_as_float(((unsigned)u) << 16);
}
static __device__ __forceinline__ unsigned short f2bf(float x) {
  unsigned u = __float_as_uint(x);
  return (unsigned short)((u + 0x7FFF + ((u >> 16) & 1)) >> 16);  // RNE
}
static __device__ __forceinline__ unsigned pack2bf(float a, float b) {
  return (unsigned)f2bf(a) | ((unsigned)f2bf(b) << 16);
}

// ---------------- preprocessing ----------------
__global__ void k_init(int* __restrict__ cur, int* __restrict__ dh, int n) {
  int i = blockIdx.x * NTHREADS + threadIdx.x;
  if (i < n) cur[i] = 1;        // slot 0 of each CSR row reserved for self-loop
  if (i < 256) dh[i] = 0;       // degree-bin histogram
}

// LDS-privatized histogram over idx[] (row or col), packed 2 nodes/u32 word.
// Per-block counts <= e/CB < 65536 -> no carry across halves.
__global__ __launch_bounds__(NTHREADS) void k_hist(
    const int* __restrict__ idx, int e, unsigned* __restrict__ part, int nw) {
  __shared__ unsigned hh[NHW];
  int tid = threadIdx.x;
  for (int i = tid; i < NHW; i += NTHREADS) hh[i] = 0;
  __syncthreads();
  int per = (e + CB - 1) / CB;
  int s = blockIdx.x * per;
  int en = min(e, s + per);
  for (int i = s + tid; i < en; i += NTHREADS) {
    int v = idx[i];
    atomicAdd(&hh[v >> 1], (v & 1) ? 0x10000u : 1u);
  }
  __syncthreads();
  unsigned* dst = part + (size_t)blockIdx.x * NHW;
  for (int i = tid; i < nw; i += NTHREADS) dst[i] = hh[i];
}

// unpack-sum the CB partial histograms -> cnt (rows) and deg (cols), +1 self-loop
__global__ void k_hmerge(const unsigned* __restrict__ partR,
                         const unsigned* __restrict__ partC,
                         int* __restrict__ cnt, int* __restrict__ deg,
                         int n, int nw) {
  int w = blockIdx.x * NTHREADS + threadIdx.x;
  if (w >= nw) return;
  unsigned lr = 0, hr = 0, lc = 0, hc = 0;
#pragma unroll 4
  for (int b = 0; b < CB; ++b) {
    unsigned pr = partR[(size_t)b * NHW + w];
    unsigned pc = partC[(size_t)b * NHW + w];
    lr += pr & 0xFFFFu; hr += pr >> 16;
    lc += pc & 0xFFFFu; hc += pc >> 16;
  }
  int i0 = 2 * w, i1 = 2 * w + 1;
  if (i0 < n) { cnt[i0] = 1 + (int)lr; deg[i0] = 1 + (int)lc; }
  if (i1 < n) { cnt[i1] = 1 + (int)hr; deg[i1] = 1 + (int)hc; }
}

__global__ void k_dis(const int* __restrict__ deg, float* __restrict__ dis,
                      float* __restrict__ selfval, int n) {
  int i = blockIdx.x * NTHREADS + threadIdx.x;
  if (i < n) {
    float d = (float)deg[i];
    dis[i] = rsqrtf(d);
    selfval[i] = 1.0f / d;        // dis[i]^2 for the self-loop edge
  }
}

__global__ void k_scan1(const int* __restrict__ cnt, int* __restrict__ rp,
                        int* __restrict__ bsum, int n) {
  __shared__ int sh[NTHREADS];
  int t = threadIdx.x;
  int i = blockIdx.x * NTHREADS + t;
  int v = (i < n) ? cnt[i] : 0;
  sh[t] = v;
  __syncthreads();
  for (int ofs = 1; ofs < NTHREADS; ofs <<= 1) {
    int u = (t >= ofs) ? sh[t - ofs] : 0;
    __syncthreads();
    sh[t] += u;
    __syncthreads();
  }
  if (i < n) rp[i] = sh[t] - v;
  if (t == NTHREADS - 1) bsum[blockIdx.x] = sh[t];
}

__global__ void k_scan2(int* __restrict__ bsum, int nb) {  // nb <= 256
  __shared__ int sh[NTHREADS];
  int t = threadIdx.x;
  int v = (t < nb) ? bsum[t] : 0;
  sh[t] = v;
  __syncthreads();
  for (int ofs = 1; ofs < NTHREADS; ofs <<= 1) {
    int u = (t >= ofs) ? sh[t - ofs] : 0;
    __syncthreads();
    sh[t] += u;
    __syncthreads();
  }
  if (t < nb) bsum[t] = sh[t] - v;
}

__global__ void k_scan3(int* __restrict__ rp, const int* __restrict__ bsum,
                        int n, int etot) {
  int i = blockIdx.x * NTHREADS + threadIdx.x;
  if (i < n) rp[i] += bsum[blockIdx.x];
  if (i == 0) rp[n] = etot;
}

// fill reserved slot 0 of each row with the self-loop edge
__global__ void k_self(const int* __restrict__ rp, const float* __restrict__ sv,
                       int2* __restrict__ ev, int n) {
  int i = blockIdx.x * NTHREADS + threadIdx.x;
  if (i < n) {
    int2 v;
    v.x = i;
    v.y = __float_as_int(sv[i]);
    ev[rp[i]] = v;
  }
}

__global__ void k_scatter(const int* __restrict__ row, const int* __restrict__ col,
                          const int* __restrict__ rp, int* __restrict__ cur,
                          const float* __restrict__ dis, int2* __restrict__ ev,
                          int e) {
  int i = blockIdx.x * NTHREADS + threadIdx.x;
  if (i < e) {
    int r = row[i], c = col[i];
    int p = rp[r] + atomicAdd(cur + r, 1);
    int2 v;
    v.x = c;
    v.y = __float_as_int(dis[r] * dis[c]);
    ev[p] = v;
  }
}

// ---- degree-bin counting sort of rows (load balance for k_spmm) ----
__global__ void k_dhist(const int* __restrict__ cnt, int* __restrict__ dh, int n) {
  __shared__ int lh[256];
  int t = threadIdx.x;
  lh[t] = 0;
  __syncthreads();
  int i = blockIdx.x * NTHREADS + t;
  if (i < n) atomicAdd(&lh[min(cnt[i], 255)], 1);
  __syncthreads();
  if (lh[t]) atomicAdd(&dh[t], lh[t]);
}

__global__ void k_dscan(const int* __restrict__ dh, int* __restrict__ dcur) {
  __shared__ int sh[256];
  int t = threadIdx.x;
  int v = dh[t];
  sh[t] = v;
  __syncthreads();
  for (int ofs = 1; ofs < 256; ofs <<= 1) {
    int u = (t >= ofs) ? sh[t - ofs] : 0;
    __syncthreads();
    sh[t] += u;
    __syncthreads();
  }
  dcur[t] = sh[t] - v;   // exclusive
}

__global__ void k_dscatter(const int* __restrict__ cnt, int* __restrict__ dcur,
                           int* __restrict__ rord, int n) {
  int i = blockIdx.x * NTHREADS + threadIdx.x;
  if (i < n) {
    int b = min(cnt[i], 255);
    rord[atomicAdd(&dcur[b], 1)] = i;
  }
}

// wT_bf16[l][f][k] = bf16(conv_w[l][k][f])  (transposed for MFMA B-fragments)
__global__ void k_wprime(const float* __restrict__ cw,
                         unsigned short* __restrict__ wTb) {
  int l = blockIdx.y;
  int idx = blockIdx.x * NTHREADS + threadIdx.x;   // 0..9215 = f*96 + k
  int f = idx / HID, k = idx % HID;
  wTb[l * HID * HID + idx] = f2bf(cw[l * HID * HID + k * HID + f]);
}

// ---------------- h0 = relu(x @ w0^T + b0) -> x0f (fp32) + hb0 (bf16) ----------
__global__ __launch_bounds__(NTHREADS) void k_lin0(
    const float* __restrict__ x, const float* __restrict__ w0,
    const float* __restrict__ b0, float* __restrict__ x0f,
    unsigned short* __restrict__ hb0, int n) {
  __shared__ float wl[INF * HID];   // wl[c][h], stride 96
  __shared__ float xT[INF * 68];    // xT[c][r], padded stride 68
  int tid = threadIdx.x;
#pragma unroll
  for (int i = 0; i < 6; ++i) {     // w0: 96x64 = 1536 float4
    int idx = tid + i * NTHREADS;
    int hrow = idx / 16, q = idx % 16;
    float4 v = *(const float4*)(w0 + hrow * INF + q * 4);
    wl[(q * 4 + 0) * HID + hrow] = v.x;
    wl[(q * 4 + 1) * HID + hrow] = v.y;
    wl[(q * 4 + 2) * HID + hrow] = v.z;
    wl[(q * 4 + 3) * HID + hrow] = v.w;
  }
  int r0 = blockIdx.x * 64;
#pragma unroll
  for (int i = 0; i < 4; ++i) {     // x tile: 64x64 = 1024 float4
    int idx = tid + i * NTHREADS;
    int r = idx / 16, q = idx % 16;
    int gr = r0 + r;
    float4 v = make_float4(0.f, 0.f, 0.f, 0.f);
    if (gr < n) v = *(const float4*)(x + (size_t)gr * INF + q * 4);
    xT[(q * 4 + 0) * 68 + r] = v.x;
    xT[(q * 4 + 1) * 68 + r] = v.y;
    xT[(q * 4 + 2) * 68 + r] = v.z;
    xT[(q * 4 + 3) * 68 + r] = v.w;
  }
  __syncthreads();
  int rg = tid & 15, cg = tid >> 4;
  float acc[4][6];
#pragma unroll
  for (int i = 0; i < 4; ++i)
#pragma unroll
    for (int j = 0; j < 6; ++j) acc[i][j] = 0.f;
#pragma unroll 4
  for (int k = 0; k < INF; ++k) {
    float4 s4 = *(const float4*)(xT + k * 68 + rg * 4);
    const float2* w2 = (const float2*)(wl + k * HID + cg * 6);
    float2 wa = w2[0], wb = w2[1], wc = w2[2];
    float wv[6] = {wa.x, wa.y, wb.x, wb.y, wc.x, wc.y};
    float sv[4] = {s4.x, s4.y, s4.z, s4.w};
#pragma unroll
    for (int i = 0; i < 4; ++i)
#pragma unroll
      for (int j = 0; j < 6; ++j) acc[i][j] = fmaf(sv[i], wv[j], acc[i][j]);
  }
  float bb[6];
#pragma unroll
  for (int j = 0; j < 6; ++j) bb[j] = b0[cg * 6 + j];
#pragma unroll
  for (int i = 0; i < 4; ++i) {
    int gr = r0 + rg * 4 + i;
    if (gr < n) {
      float r_[6];
#pragma unroll
      for (int j = 0; j < 6; ++j) r_[j] = fmaxf(acc[i][j] + bb[j], 0.f);
      float* o = x0f + (size_t)gr * HID + cg * 6;
#pragma unroll
      for (int j = 0; j < 6; ++j) o[j] = r_[j];
      unsigned* ob = (unsigned*)(hb0 + (size_t)gr * HID + cg * 6);
      ob[0] = pack2bf(r_[0], r_[1]);
      ob[1] = pack2bf(r_[2], r_[3]);
      ob[2] = pack2bf(r_[4], r_[5]);
    }
  }
}

// ------- SpMM + residual: s = 0.9*(A_hat h) + 0.1*x0 ------------------------
// half-wave per row (rows via degree-sorted rord -> uniform work per block);
// 32 lanes = 8 edge-slots x 4 feature-groups (24 feats each).
__global__ __launch_bounds__(NTHREADS) void k_spmm(
    const unsigned short* __restrict__ hin, const float* __restrict__ x0,
    float* __restrict__ sout, const int* __restrict__ rp,
    const int2* __restrict__ ev, const int* __restrict__ rord, int n) {
  __shared__ float red[8][8][100];
  int t = threadIdx.x;
  int hw = t >> 5;            // half-wave id 0..7 (one row each)
  int lane = t & 31;
  int eb = lane >> 2;         // edge slot 0..7
  int fg = lane & 3;          // feature group 0..3 (24 features)
  int idx = blockIdx.x * 8 + hw;
  int r = (idx < n) ? rord[idx] : rord[0];  // dup row 0 for tail: benign rewrite
  int e0 = rp[r], e1 = rp[r + 1];   // >= 1 edge always (self-loop)
  float acc[24];
#pragma unroll
  for (int j = 0; j < 24; ++j) acc[j] = 0.f;

  int idx0 = e0 + eb;
  bool ok = idx0 < e1;
  idx0 = ok ? idx0 : e1 - 1;
  int2 cv = ev[idx0];
  for (int base = e0; base < e1; base += 8) {
    int2 cur = cv;
    bool okc = ok;
    int nb = base + 8;
    if (nb < e1) {            // prefetch next batch of edges
      int i2 = nb + eb;
      ok = i2 < e1;
      i2 = ok ? i2 : e1 - 1;
      cv = ev[i2];
    }
    float v = okc ? __int_as_float(cur.y) : 0.f;
    const unsigned short* hc = hin + (size_t)cur.x * HID + fg * 24;
    ushort8_t p0 = *(const ushort8_t*)(hc);
    ushort8_t p1 = *(const ushort8_t*)(hc + 8);
    ushort8_t p2 = *(const ushort8_t*)(hc + 16);
#pragma unroll
    for (int j = 0; j < 8; ++j) acc[j]      = fmaf(v, bf2f(p0[j]), acc[j]);
#pragma unroll
    for (int j = 0; j < 8; ++j) acc[8 + j]  = fmaf(v, bf2f(p1[j]), acc[8 + j]);
#pragma unroll
    for (int j = 0; j < 8; ++j) acc[16 + j] = fmaf(v, bf2f(p2[j]), acc[16 + j]);
  }
  // partial sums -> LDS
  float* myr = &red[hw][eb][fg * 24];
#pragma unroll
  for (int j = 0; j < 6; ++j)
    *(float4*)(myr + j * 4) =
        make_float4(acc[j * 4], acc[j * 4 + 1], acc[j * 4 + 2], acc[j * 4 + 3]);
  __syncthreads();
  // lanes 0..23 of each half-wave: sum 8 edge-slot copies of 4 features each
  if (lane < 24) {
    float4 tot = *(const float4*)(&red[hw][0][lane * 4]);
#pragma unroll
    for (int b = 1; b < 8; ++b) {
      float4 p = *(const float4*)(&red[hw][b][lane * 4]);
      tot.x += p.x; tot.y += p.y; tot.z += p.z; tot.w += p.w;
    }
    size_t o = (size_t)r * HID + lane * 4;
    float4 xr = *(const float4*)(x0 + o);
    float4 s4;
    s4.x = 0.9f * tot.x + 0.1f * xr.x;
    s4.y = 0.9f * tot.y + 0.1f * xr.y;
    s4.z = 0.9f * tot.z + 0.1f * xr.z;
    s4.w = 0.9f * tot.w + 0.1f * xr.w;
    *(float4*)(sout + o) = s4;
  }
}

// -------- h' = relu((1-b)*s + b*(s @ w)), MFMA bf16, s fp32, 64 rows/block -----
__global__ __launch_bounds__(NTHREADS) void k_gemm(
    const float* __restrict__ s, const unsigned short* __restrict__ wT,
    unsigned short* __restrict__ hout, float omb, float beta, int n) {
  __shared__ float sT[64 * 100];          // [r][k] fp32, stride 100 (pad)
  __shared__ unsigned short wl[HID * 104]; // [f][k] bf16, stride 104 (pad)
  int tid = threadIdx.x;
  int r0 = blockIdx.x * 64;
  {  // stage s: thread -> (row = tid>>2, 24-feat chunk = tid&3)
    int r = tid >> 2, c = (tid & 3) * 24;
    int gr = r0 + r;
    const float* src = s + (size_t)gr * HID + c;
    float* dst = sT + r * 100 + c;
    if (gr < n) {
#pragma unroll
      for (int j = 0; j < 6; ++j) *(float4*)(dst + j * 4) = *(const float4*)(src + j * 4);
    } else {
#pragma unroll
      for (int j = 0; j < 6; ++j) *(float4*)(dst + j * 4) = make_float4(0.f, 0.f, 0.f, 0.f);
    }
  }
  {  // stage wT: 96x96 bf16 = 1152 ushort8
#pragma unroll
    for (int i = 0; i < 5; ++i) {
      int idx = tid + i * NTHREADS;
      if (idx < 1152) {
        int f = idx / 12, c = (idx % 12) * 8;
        ushort8_t v = *(const ushort8_t*)(wT + f * HID + c);
        *(ushort8_t*)(wl + f * 104 + c) = v;
      }
    }
  }
  __syncthreads();
  int lane = tid & 63, wave = tid >> 6;
  int l15 = lane & 15;      // A-row / B-col / C-col
  int kg = lane >> 4;       // k-group 0..3
  f32x4_t acc[6];
#pragma unroll
  for (int i = 0; i < 6; ++i) acc[i] = (f32x4_t)(0.f);
#pragma unroll
  for (int kt = 0; kt < 3; ++kt) {
    const float* ap = sT + (wave * 16 + l15) * 100 + kt * 32 + kg * 8;
    float4 a0 = *(const float4*)(ap);
    float4 a1 = *(const float4*)(ap + 4);
    union { short8_t s8; unsigned u[4]; } A;
    A.u[0] = pack2bf(a0.x, a0.y);
    A.u[1] = pack2bf(a0.z, a0.w);
    A.u[2] = pack2bf(a1.x, a1.y);
    A.u[3] = pack2bf(a1.z, a1.w);
#pragma unroll
    for (int ft = 0; ft < 6; ++ft) {
      short8_t B = *(const short8_t*)(wl + (ft * 16 + l15) * 104 + kt * 32 + kg * 8);
      acc[ft] = __builtin_amdgcn_mfma_f32_16x16x32_bf16(A.s8, B, acc[ft], 0, 0, 0);
    }
  }
  // epilogue: C layout col = lane&15, row = (lane>>4)*4 + j   [m89-verified]
#pragma unroll
  for (int ft = 0; ft < 6; ++ft) {
    int col = ft * 16 + l15;
#pragma unroll
    for (int j = 0; j < 4; ++j) {
      int rl = wave * 16 + kg * 4 + j;
      int gr = r0 + rl;
      float sv = sT[rl * 100 + col];
      float o = fmaxf(omb * sv + beta * acc[ft][j], 0.f);
      if (gr < n) hout[(size_t)gr * HID + col] = f2bf(o);
    }
  }
}

// ---------------- out = h @ w1^T + b1  (h is bf16) ----------------
__global__ __launch_bounds__(NTHREADS) void k_lin1(
    const unsigned short* __restrict__ h, const float* __restrict__ w1,
    const float* __restrict__ b1, float* __restrict__ out, int n) {
  __shared__ float hT[HID * 68];    // [k][r]
  __shared__ float w1l[HID * OUTF]; // [k][o]
  int tid = threadIdx.x;
#pragma unroll
  for (int i = 0; i < 6; ++i) {     // w1: 16x96 = 1536 floats
    int idx = tid + i * NTHREADS;
    int o = idx / HID, k = idx % HID;
    w1l[k * OUTF + o] = w1[idx];
  }
  int r0 = blockIdx.x * 64;
#pragma unroll
  for (int i = 0; i < 3; ++i) {     // h tile: 64x96 bf16 = 768 ushort8
    int idx = tid + i * NTHREADS;
    int r = idx / 12, q = idx % 12;
    int gr = r0 + r;
    ushort8_t v = (ushort8_t)0;
    if (gr < n) v = *(const ushort8_t*)(h + (size_t)gr * HID + q * 8);
#pragma unroll
    for (int j = 0; j < 8; ++j) hT[(q * 8 + j) * 68 + r] = bf2f(v[j]);
  }
  __syncthreads();
  int r = tid & 63, og = tid >> 6;
  float acc[4] = {0.f, 0.f, 0.f, 0.f};
#pragma unroll 4
  for (int k = 0; k < HID; ++k) {
    float s = hT[k * 68 + r];
    float4 w4 = *(const float4*)(w1l + k * OUTF + og * 4);
    acc[0] = fmaf(s, w4.x, acc[0]);
    acc[1] = fmaf(s, w4.y, acc[1]);
    acc[2] = fmaf(s, w4.z, acc[2]);
    acc[3] = fmaf(s, w4.w, acc[3]);
  }
  int gr = r0 + r;
  if (gr < n) {
    float* op = out + (size_t)gr * OUTF + og * 4;
#pragma unroll
    for (int j = 0; j < 4; ++j) op[j] = acc[j] + b1[og * 4 + j];
  }
}

extern "C" void kernel_launch(void* const* d_in, const int* in_sizes, int n_in,
                              void* d_out, int out_size, void* d_ws, size_t ws_size,
                              hipStream_t stream) {
  const float* x  = (const float*)d_in[0];
  const int*   ei = (const int*)d_in[1];     // [2][E]: rows then cols
  const float* w0 = (const float*)d_in[2];
  const float* b0 = (const float*)d_in[3];
  const float* w1 = (const float*)d_in[4];
  const float* b1 = (const float*)d_in[5];
  const float* cw = (const float*)d_in[6];
  int n = in_sizes[0] / INF;    // 50000
  int e = in_sizes[1] / 2;      // 800000
  const int* row = ei;
  const int* col = ei + e;

  char* ws = (char*)d_ws;
  size_t off = 0;
  auto alloc = [&](size_t bytes) -> void* {
    void* p = (void*)(ws + off);
    off += (bytes + 255) & ~(size_t)255;
    return p;
  };
  float*          x0f = (float*)alloc((size_t)n * HID * 4);
  float*          sbuf= (float*)alloc((size_t)n * HID * 4);
  unsigned short* hbA = (unsigned short*)alloc((size_t)n * HID * 2);
  unsigned short* hbB = (unsigned short*)alloc((size_t)n * HID * 2);
  unsigned short* wTb = (unsigned short*)alloc((size_t)NLAYERS * HID * HID * 2);
  int*   deg  = (int*)alloc((size_t)n * 4);
  float* dis  = (float*)alloc((size_t)n * 4);
  float* sv   = (float*)alloc((size_t)n * 4);
  int*   cnt  = (int*)alloc((size_t)n * 4);
  int*   cur  = (int*)alloc((size_t)n * 4);
  int*   rp   = (int*)alloc((size_t)(n + 1) * 4);
  int2*  ev   = (int2*)alloc((size_t)(e + n) * 8);  // + self-loop slots
  int*   bsum = (int*)alloc(1024 * 4);
  int*   rord = (int*)alloc((size_t)(n + 8) * 4);
  int*   dh   = (int*)alloc(256 * 4);
  int*   dcur = (int*)alloc(256 * 4);
  // partial histograms alias sbuf (12.9 MB <= 19.2 MB; sbuf unused until layer 0)
  unsigned* partR = (unsigned*)sbuf;
  unsigned* partC = partR + (size_t)CB * NHW;
  int nw = (n + 1) / 2;         // packed words (<= NHW)
  (void)ws_size; (void)n_in; (void)out_size;

  int nb  = (n + NTHREADS - 1) / NTHREADS;   // 196
  int ebl = (e + NTHREADS - 1) / NTHREADS;   // 3125
  int r64 = (n + 63) / 64;                   // 782

  k_init<<<nb, NTHREADS, 0, stream>>>(cur, dh, n);
  k_hist<<<CB, NTHREADS, 0, stream>>>(row, e, partR, nw);
  k_hist<<<CB, NTHREADS, 0, stream>>>(col, e, partC, nw);
  k_hmerge<<<(nw + NTHREADS - 1) / NTHREADS, NTHREADS, 0, stream>>>(
      partR, partC, cnt, deg, n, nw);
  k_dis<<<nb, NTHREADS, 0, stream>>>(deg, dis, sv, n);
  k_scan1<<<nb, NTHREADS, 0, stream>>>(cnt, rp, bsum, n);
  k_scan2<<<1, NTHREADS, 0, stream>>>(bsum, nb);
  k_scan3<<<nb, NTHREADS, 0, stream>>>(rp, bsum, n, e + n);
  k_self<<<nb, NTHREADS, 0, stream>>>(rp, sv, ev, n);
  k_scatter<<<ebl, NTHREADS, 0, stream>>>(row, col, rp, cur, dis, ev, e);
  k_dhist<<<nb, NTHREADS, 0, stream>>>(cnt, dh, n);
  k_dscan<<<1, 256, 0, stream>>>(dh, dcur);
  k_dscatter<<<nb, NTHREADS, 0, stream>>>(cnt, dcur, rord, n);
  k_wprime<<<dim3(36, NLAYERS), NTHREADS, 0, stream>>>(cw, wTb);
  k_lin0<<<r64, NTHREADS, 0, stream>>>(x, w0, b0, x0f, hbA, n);

  const unsigned short* hin = hbA;
  for (int l = 0; l < NLAYERS; ++l) {
    unsigned short* hout = (l & 1) ? hbA : hbB;
    float beta = logf(0.5f / (float)(l + 1) + 1.0f);
    k_spmm<<<(n + 7) / 8, NTHREADS, 0, stream>>>(hin, x0f, sbuf, rp, ev, rord, n);
    k_gemm<<<r64, NTHREADS, 0, stream>>>(sbuf, wTb + (size_t)l * HID * HID,
                                         hout, 1.0f - beta, beta, n);
    hin = hout;
  }
  k_lin1<<<r64, NTHREADS, 0, stream>>>(hin, w1, b1, (float*)d_out, n);
}

// Round 6
// 774.553 us; speedup vs baseline: 1.2401x; 1.2401x over previous
//
#include <hip/hip_runtime.h>

#define NTHREADS 256
#define HID 96
#define INF 64
#define OUTF 16
#define NLAYERS 16
#define NHW 25088     // packed histogram words (2 nodes/word), fits n<=50176
#define CB 64         // histogram blocks

typedef __attribute__((ext_vector_type(8))) unsigned short ushort8_t;
typedef __attribute__((ext_vector_type(8))) short short8_t;   // MFMA bf16 A/B frag
typedef __attribute__((ext_vector_type(4))) float f32x4_t;    // MFMA C/D frag

static __device__ __forceinline__ float bf2f(unsigned short u) {
  return __uint_as_float(((unsigned)u) << 16);
}
static __device__ __forceinline__ unsigned short f2bf(float x) {
  unsigned u = __float_as_uint(x);
  return (unsigned short)((u + 0x7FFF + ((u >> 16) & 1)) >> 16);  // RNE
}
static __device__ __forceinline__ unsigned pack2bf(float a, float b) {
  return (unsigned)f2bf(a) | ((unsigned)f2bf(b) << 16);
}

// ---------------- preprocessing ----------------
__global__ void k_init(int* __restrict__ cur, int n) {
  int i = blockIdx.x * NTHREADS + threadIdx.x;
  if (i < n) cur[i] = 1;        // slot 0 of each CSR row reserved for self-loop
}

// LDS-privatized histogram over idx[] (row or col), packed 2 nodes/u32 word.
// Per-block counts <= e/CB < 65536 -> no carry across halves.
__global__ __launch_bounds__(NTHREADS) void k_hist(
    const int* __restrict__ idx, int e, unsigned* __restrict__ part, int nw) {
  __shared__ unsigned hh[NHW];
  int tid = threadIdx.x;
  for (int i = tid; i < NHW; i += NTHREADS) hh[i] = 0;
  __syncthreads();
  int per = (e + CB - 1) / CB;
  int s = blockIdx.x * per;
  int en = min(e, s + per);
  for (int i = s + tid; i < en; i += NTHREADS) {
    int v = idx[i];
    atomicAdd(&hh[v >> 1], (v & 1) ? 0x10000u : 1u);
  }
  __syncthreads();
  unsigned* dst = part + (size_t)blockIdx.x * NHW;
  for (int i = tid; i < nw; i += NTHREADS) dst[i] = hh[i];
}

// unpack-sum the CB partial histograms -> cnt (rows) and deg (cols), +1 self-loop
__global__ void k_hmerge(const unsigned* __restrict__ partR,
                         const unsigned* __restrict__ partC,
                         int* __restrict__ cnt, int* __restrict__ deg,
                         int n, int nw) {
  int w = blockIdx.x * NTHREADS + threadIdx.x;
  if (w >= nw) return;
  unsigned lr = 0, hr = 0, lc = 0, hc = 0;
#pragma unroll 4
  for (int b = 0; b < CB; ++b) {
    unsigned pr = partR[(size_t)b * NHW + w];
    unsigned pc = partC[(size_t)b * NHW + w];
    lr += pr & 0xFFFFu; hr += pr >> 16;
    lc += pc & 0xFFFFu; hc += pc >> 16;
  }
  int i0 = 2 * w, i1 = 2 * w + 1;
  if (i0 < n) { cnt[i0] = 1 + (int)lr; deg[i0] = 1 + (int)lc; }
  if (i1 < n) { cnt[i1] = 1 + (int)hr; deg[i1] = 1 + (int)hc; }
}

__global__ void k_dis(const int* __restrict__ deg, float* __restrict__ dis,
                      float* __restrict__ selfval, int n) {
  int i = blockIdx.x * NTHREADS + threadIdx.x;
  if (i < n) {
    float d = (float)deg[i];
    dis[i] = rsqrtf(d);
    selfval[i] = 1.0f / d;        // dis[i]^2 for the self-loop edge
  }
}

__global__ void k_scan1(const int* __restrict__ cnt, int* __restrict__ rp,
                        int* __restrict__ bsum, int n) {
  __shared__ int sh[NTHREADS];
  int t = threadIdx.x;
  int i = blockIdx.x * NTHREADS + t;
  int v = (i < n) ? cnt[i] : 0;
  sh[t] = v;
  __syncthreads();
  for (int ofs = 1; ofs < NTHREADS; ofs <<= 1) {
    int u = (t >= ofs) ? sh[t - ofs] : 0;
    __syncthreads();
    sh[t] += u;
    __syncthreads();
  }
  if (i < n) rp[i] = sh[t] - v;
  if (t == NTHREADS - 1) bsum[blockIdx.x] = sh[t];
}

__global__ void k_scan2(int* __restrict__ bsum, int nb) {  // nb <= 256
  __shared__ int sh[NTHREADS];
  int t = threadIdx.x;
  int v = (t < nb) ? bsum[t] : 0;
  sh[t] = v;
  __syncthreads();
  for (int ofs = 1; ofs < NTHREADS; ofs <<= 1) {
    int u = (t >= ofs) ? sh[t - ofs] : 0;
    __syncthreads();
    sh[t] += u;
    __syncthreads();
  }
  if (t < nb) bsum[t] = sh[t] - v;
}

__global__ void k_scan3(int* __restrict__ rp, const int* __restrict__ bsum,
                        int n, int etot) {
  int i = blockIdx.x * NTHREADS + threadIdx.x;
  if (i < n) rp[i] += bsum[blockIdx.x];
  if (i == 0) rp[n] = etot;
}

// fill reserved slot 0 of each row with the self-loop edge
__global__ void k_self(const int* __restrict__ rp, const float* __restrict__ sv,
                       int2* __restrict__ ev, int n) {
  int i = blockIdx.x * NTHREADS + threadIdx.x;
  if (i < n) {
    int2 v;
    v.x = i;
    v.y = __float_as_int(sv[i]);
    ev[rp[i]] = v;
  }
}

__global__ void k_scatter(const int* __restrict__ row, const int* __restrict__ col,
                          const int* __restrict__ rp, int* __restrict__ cur,
                          const float* __restrict__ dis, int2* __restrict__ ev,
                          int e) {
  int i = blockIdx.x * NTHREADS + threadIdx.x;
  if (i < e) {
    int r = row[i], c = col[i];
    int p = rp[r] + atomicAdd(cur + r, 1);
    int2 v;
    v.x = c;
    v.y = __float_as_int(dis[r] * dis[c]);
    ev[p] = v;
  }
}

// wT_bf16[l][f][k] = bf16(conv_w[l][k][f])  (transposed for MFMA B-fragments)
__global__ void k_wprime(const float* __restrict__ cw,
                         unsigned short* __restrict__ wTb) {
  int l = blockIdx.y;
  int idx = blockIdx.x * NTHREADS + threadIdx.x;   // 0..9215 = f*96 + k
  int f = idx / HID, k = idx % HID;
  wTb[l * HID * HID + idx] = f2bf(cw[l * HID * HID + k * HID + f]);
}

// ---------------- h0 = relu(x @ w0^T + b0) -> x0f (fp32) + hb0 (bf16) ----------
__global__ __launch_bounds__(NTHREADS) void k_lin0(
    const float* __restrict__ x, const float* __restrict__ w0,
    const float* __restrict__ b0, float* __restrict__ x0f,
    unsigned short* __restrict__ hb0, int n) {
  __shared__ float wl[INF * HID];   // wl[c][h], stride 96
  __shared__ float xT[INF * 68];    // xT[c][r], padded stride 68
  int tid = threadIdx.x;
#pragma unroll
  for (int i = 0; i < 6; ++i) {     // w0: 96x64 = 1536 float4
    int idx = tid + i * NTHREADS;
    int hrow = idx / 16, q = idx % 16;
    float4 v = *(const float4*)(w0 + hrow * INF + q * 4);
    wl[(q * 4 + 0) * HID + hrow] = v.x;
    wl[(q * 4 + 1) * HID + hrow] = v.y;
    wl[(q * 4 + 2) * HID + hrow] = v.z;
    wl[(q * 4 + 3) * HID + hrow] = v.w;
  }
  int r0 = blockIdx.x * 64;
#pragma unroll
  for (int i = 0; i < 4; ++i) {     // x tile: 64x64 = 1024 float4
    int idx = tid + i * NTHREADS;
    int r = idx / 16, q = idx % 16;
    int gr = r0 + r;
    float4 v = make_float4(0.f, 0.f, 0.f, 0.f);
    if (gr < n) v = *(const float4*)(x + (size_t)gr * INF + q * 4);
    xT[(q * 4 + 0) * 68 + r] = v.x;
    xT[(q * 4 + 1) * 68 + r] = v.y;
    xT[(q * 4 + 2) * 68 + r] = v.z;
    xT[(q * 4 + 3) * 68 + r] = v.w;
  }
  __syncthreads();
  int rg = tid & 15, cg = tid >> 4;
  float acc[4][6];
#pragma unroll
  for (int i = 0; i < 4; ++i)
#pragma unroll
    for (int j = 0; j < 6; ++j) acc[i][j] = 0.f;
#pragma unroll 4
  for (int k = 0; k < INF; ++k) {
    float4 s4 = *(const float4*)(xT + k * 68 + rg * 4);
    const float2* w2 = (const float2*)(wl + k * HID + cg * 6);
    float2 wa = w2[0], wb = w2[1], wc = w2[2];
    float wv[6] = {wa.x, wa.y, wb.x, wb.y, wc.x, wc.y};
    float sv[4] = {s4.x, s4.y, s4.z, s4.w};
#pragma unroll
    for (int i = 0; i < 4; ++i)
#pragma unroll
      for (int j = 0; j < 6; ++j) acc[i][j] = fmaf(sv[i], wv[j], acc[i][j]);
  }
  float bb[6];
#pragma unroll
  for (int j = 0; j < 6; ++j) bb[j] = b0[cg * 6 + j];
#pragma unroll
  for (int i = 0; i < 4; ++i) {
    int gr = r0 + rg * 4 + i;
    if (gr < n) {
      float r_[6];
#pragma unroll
      for (int j = 0; j < 6; ++j) r_[j] = fmaxf(acc[i][j] + bb[j], 0.f);
      float* o = x0f + (size_t)gr * HID + cg * 6;
#pragma unroll
      for (int j = 0; j < 6; ++j) o[j] = r_[j];
      unsigned* ob = (unsigned*)(hb0 + (size_t)gr * HID + cg * 6);
      ob[0] = pack2bf(r_[0], r_[1]);
      ob[1] = pack2bf(r_[2], r_[3]);
      ob[2] = pack2bf(r_[4], r_[5]);
    }
  }
}

// ------- SpMM + residual: s = 0.9*(A_hat h) + 0.1*x0 ------------------------
// half-wave per row (natural order: streaming-friendly ev/x0/sout access);
// 32 lanes = 8 edge-slots x 4 feature-groups (24 feats each).
// Reduction is INTRA-WAVE (red[hw] written+read by the same wave64), so no
// block-wide __syncthreads: lgkmcnt(0)+wave_barrier suffices -> no cross-wave
// rendezvous on the slowest row.
__global__ __launch_bounds__(NTHREADS) void k_spmm(
    const unsigned short* __restrict__ hin, const float* __restrict__ x0,
    float* __restrict__ sout, const int* __restrict__ rp,
    const int2* __restrict__ ev, int n) {
  __shared__ float red[8][8][100];
  int t = threadIdx.x;
  int hw = t >> 5;            // half-wave id 0..7 (one row each)
  int lane = t & 31;
  int eb = lane >> 2;         // edge slot 0..7
  int fg = lane & 3;          // feature group 0..3 (24 features)
  int r = blockIdx.x * 8 + hw;
  if (r >= n) r = n - 1;      // clamp: duplicate work, benign same-value write
  int e0 = rp[r], e1 = rp[r + 1];   // >= 1 edge always (self-loop)
  float acc[24];
#pragma unroll
  for (int j = 0; j < 24; ++j) acc[j] = 0.f;

  int idx0 = e0 + eb;
  bool ok = idx0 < e1;
  idx0 = ok ? idx0 : e1 - 1;
  int2 cv = ev[idx0];
  for (int base = e0; base < e1; base += 8) {
    int2 cur = cv;
    bool okc = ok;
    int nb = base + 8;
    if (nb < e1) {            // prefetch next batch of edges
      int i2 = nb + eb;
      ok = i2 < e1;
      i2 = ok ? i2 : e1 - 1;
      cv = ev[i2];
    }
    float v = okc ? __int_as_float(cur.y) : 0.f;
    const unsigned short* hc = hin + (size_t)cur.x * HID + fg * 24;
    ushort8_t p0 = *(const ushort8_t*)(hc);
    ushort8_t p1 = *(const ushort8_t*)(hc + 8);
    ushort8_t p2 = *(const ushort8_t*)(hc + 16);
#pragma unroll
    for (int j = 0; j < 8; ++j) acc[j]      = fmaf(v, bf2f(p0[j]), acc[j]);
#pragma unroll
    for (int j = 0; j < 8; ++j) acc[8 + j]  = fmaf(v, bf2f(p1[j]), acc[8 + j]);
#pragma unroll
    for (int j = 0; j < 8; ++j) acc[16 + j] = fmaf(v, bf2f(p2[j]), acc[16 + j]);
  }
  // partial sums -> LDS (consumed only by this same wave)
  float* myr = &red[hw][eb][fg * 24];
#pragma unroll
  for (int j = 0; j < 6; ++j)
    *(float4*)(myr + j * 4) =
        make_float4(acc[j * 4], acc[j * 4 + 1], acc[j * 4 + 2], acc[j * 4 + 3]);
  asm volatile("s_waitcnt lgkmcnt(0)" ::: "memory");
  __builtin_amdgcn_wave_barrier();
  // lanes 0..23 of each half-wave: sum 8 edge-slot copies of 4 features each
  if (lane < 24) {
    float4 tot = *(const float4*)(&red[hw][0][lane * 4]);
#pragma unroll
    for (int b = 1; b < 8; ++b) {
      float4 p = *(const float4*)(&red[hw][b][lane * 4]);
      tot.x += p.x; tot.y += p.y; tot.z += p.z; tot.w += p.w;
    }
    size_t o = (size_t)r * HID + lane * 4;
    float4 xr = *(const float4*)(x0 + o);
    float4 s4;
    s4.x = 0.9f * tot.x + 0.1f * xr.x;
    s4.y = 0.9f * tot.y + 0.1f * xr.y;
    s4.z = 0.9f * tot.z + 0.1f * xr.z;
    s4.w = 0.9f * tot.w + 0.1f * xr.w;
    *(float4*)(sout + o) = s4;
  }
}

// -------- h' = relu((1-b)*s + b*(s @ w)), MFMA bf16, s fp32, 64 rows/block -----
__global__ __launch_bounds__(NTHREADS) void k_gemm(
    const float* __restrict__ s, const unsigned short* __restrict__ wT,
    unsigned short* __restrict__ hout, float omb, float beta, int n) {
  __shared__ float sT[64 * 100];          // [r][k] fp32, stride 100 (pad)
  __shared__ unsigned short wl[HID * 104]; // [f][k] bf16, stride 104 (pad)
  int tid = threadIdx.x;
  int r0 = blockIdx.x * 64;
  {  // stage s: thread -> (row = tid>>2, 24-feat chunk = tid&3)
    int r = tid >> 2, c = (tid & 3) * 24;
    int gr = r0 + r;
    const float* src = s + (size_t)gr * HID + c;
    float* dst = sT + r * 100 + c;
    if (gr < n) {
#pragma unroll
      for (int j = 0; j < 6; ++j) *(float4*)(dst + j * 4) = *(const float4*)(src + j * 4);
    } else {
#pragma unroll
      for (int j = 0; j < 6; ++j) *(float4*)(dst + j * 4) = make_float4(0.f, 0.f, 0.f, 0.f);
    }
  }
  {  // stage wT: 96x96 bf16 = 1152 ushort8
#pragma unroll
    for (int i = 0; i < 5; ++i) {
      int idx = tid + i * NTHREADS;
      if (idx < 1152) {
        int f = idx / 12, c = (idx % 12) * 8;
        ushort8_t v = *(const ushort8_t*)(wT + f * HID + c);
        *(ushort8_t*)(wl + f * 104 + c) = v;
      }
    }
  }
  __syncthreads();
  int lane = tid & 63, wave = tid >> 6;
  int l15 = lane & 15;      // A-row / B-col / C-col
  int kg = lane >> 4;       // k-group 0..3
  f32x4_t acc[6];
#pragma unroll
  for (int i = 0; i < 6; ++i) acc[i] = (f32x4_t)(0.f);
#pragma unroll
  for (int kt = 0; kt < 3; ++kt) {
    const float* ap = sT + (wave * 16 + l15) * 100 + kt * 32 + kg * 8;
    float4 a0 = *(const float4*)(ap);
    float4 a1 = *(const float4*)(ap + 4);
    union { short8_t s8; unsigned u[4]; } A;
    A.u[0] = pack2bf(a0.x, a0.y);
    A.u[1] = pack2bf(a0.z, a0.w);
    A.u[2] = pack2bf(a1.x, a1.y);
    A.u[3] = pack2bf(a1.z, a1.w);
#pragma unroll
    for (int ft = 0; ft < 6; ++ft) {
      short8_t B = *(const short8_t*)(wl + (ft * 16 + l15) * 104 + kt * 32 + kg * 8);
      acc[ft] = __builtin_amdgcn_mfma_f32_16x16x32_bf16(A.s8, B, acc[ft], 0, 0, 0);
    }
  }
  // epilogue: C layout col = lane&15, row = (lane>>4)*4 + j   [m89-verified]
#pragma unroll
  for (int ft = 0; ft < 6; ++ft) {
    int col = ft * 16 + l15;
#pragma unroll
    for (int j = 0; j < 4; ++j) {
      int rl = wave * 16 + kg * 4 + j;
      int gr = r0 + rl;
      float sv = sT[rl * 100 + col];
      float o = fmaxf(omb * sv + beta * acc[ft][j], 0.f);
      if (gr < n) hout[(size_t)gr * HID + col] = f2bf(o);
    }
  }
}

// ---------------- out = h @ w1^T + b1  (h is bf16) ----------------
__global__ __launch_bounds__(NTHREADS) void k_lin1(
    const unsigned short* __restrict__ h, const float* __restrict__ w1,
    const float* __restrict__ b1, float* __restrict__ out, int n) {
  __shared__ float hT[HID * 68];    // [k][r]
  __shared__ float w1l[HID * OUTF]; // [k][o]
  int tid = threadIdx.x;
#pragma unroll
  for (int i = 0; i < 6; ++i) {     // w1: 16x96 = 1536 floats
    int idx = tid + i * NTHREADS;
    int o = idx / HID, k = idx % HID;
    w1l[k * OUTF + o] = w1[idx];
  }
  int r0 = blockIdx.x * 64;
#pragma unroll
  for (int i = 0; i < 3; ++i) {     // h tile: 64x96 bf16 = 768 ushort8
    int idx = tid + i * NTHREADS;
    int r = idx / 12, q = idx % 12;
    int gr = r0 + r;
    ushort8_t v = (ushort8_t)0;
    if (gr < n) v = *(const ushort8_t*)(h + (size_t)gr * HID + q * 8);
#pragma unroll
    for (int j = 0; j < 8; ++j) hT[(q * 8 + j) * 68 + r] = bf2f(v[j]);
  }
  __syncthreads();
  int r = tid & 63, og = tid >> 6;
  float acc[4] = {0.f, 0.f, 0.f, 0.f};
#pragma unroll 4
  for (int k = 0; k < HID; ++k) {
    float s = hT[k * 68 + r];
    float4 w4 = *(const float4*)(w1l + k * OUTF + og * 4);
    acc[0] = fmaf(s, w4.x, acc[0]);
    acc[1] = fmaf(s, w4.y, acc[1]);
    acc[2] = fmaf(s, w4.z, acc[2]);
    acc[3] = fmaf(s, w4.w, acc[3]);
  }
  int gr = r0 + r;
  if (gr < n) {
    float* op = out + (size_t)gr * OUTF + og * 4;
#pragma unroll
    for (int j = 0; j < 4; ++j) op[j] = acc[j] + b1[og * 4 + j];
  }
}

extern "C" void kernel_launch(void* const* d_in, const int* in_sizes, int n_in,
                              void* d_out, int out_size, void* d_ws, size_t ws_size,
                              hipStream_t stream) {
  const float* x  = (const float*)d_in[0];
  const int*   ei = (const int*)d_in[1];     // [2][E]: rows then cols
  const float* w0 = (const float*)d_in[2];
  const float* b0 = (const float*)d_in[3];
  const float* w1 = (const float*)d_in[4];
  const float* b1 = (const float*)d_in[5];
  const float* cw = (const float*)d_in[6];
  int n = in_sizes[0] / INF;    // 50000
  int e = in_sizes[1] / 2;      // 800000
  const int* row = ei;
  const int* col = ei + e;

  char* ws = (char*)d_ws;
  size_t off = 0;
  auto alloc = [&](size_t bytes) -> void* {
    void* p = (void*)(ws + off);
    off += (bytes + 255) & ~(size_t)255;
    return p;
  };
  float*          x0f = (float*)alloc((size_t)n * HID * 4);
  float*          sbuf= (float*)alloc((size_t)n * HID * 4);
  unsigned short* hbA = (unsigned short*)alloc((size_t)n * HID * 2);
  unsigned short* hbB = (unsigned short*)alloc((size_t)n * HID * 2);
  unsigned short* wTb = (unsigned short*)alloc((size_t)NLAYERS * HID * HID * 2);
  int*   deg  = (int*)alloc((size_t)n * 4);
  float* dis  = (float*)alloc((size_t)n * 4);
  float* sv   = (float*)alloc((size_t)n * 4);
  int*   cnt  = (int*)alloc((size_t)n * 4);
  int*   cur  = (int*)alloc((size_t)n * 4);
  int*   rp   = (int*)alloc((size_t)(n + 1) * 4);
  int2*  ev   = (int2*)alloc((size_t)(e + n) * 8);  // + self-loop slots
  int*   bsum = (int*)alloc(1024 * 4);
  // partial histograms alias sbuf (12.9 MB <= 19.2 MB; sbuf unused until layer 0)
  unsigned* partR = (unsigned*)sbuf;
  unsigned* partC = partR + (size_t)CB * NHW;
  int nw = (n + 1) / 2;         // packed words (<= NHW)
  (void)ws_size; (void)n_in; (void)out_size;

  int nb  = (n + NTHREADS - 1) / NTHREADS;   // 196
  int ebl = (e + NTHREADS - 1) / NTHREADS;   // 3125
  int r64 = (n + 63) / 64;                   // 782

  k_init<<<nb, NTHREADS, 0, stream>>>(cur, n);
  k_hist<<<CB, NTHREADS, 0, stream>>>(row, e, partR, nw);
  k_hist<<<CB, NTHREADS, 0, stream>>>(col, e, partC, nw);
  k_hmerge<<<(nw + NTHREADS - 1) / NTHREADS, NTHREADS, 0, stream>>>(
      partR, partC, cnt, deg, n, nw);
  k_dis<<<nb, NTHREADS, 0, stream>>>(deg, dis, sv, n);
  k_scan1<<<nb, NTHREADS, 0, stream>>>(cnt, rp, bsum, n);
  k_scan2<<<1, NTHREADS, 0, stream>>>(bsum, nb);
  k_scan3<<<nb, NTHREADS, 0, stream>>>(rp, bsum, n, e + n);
  k_self<<<nb, NTHREADS, 0, stream>>>(rp, sv, ev, n);
  k_scatter<<<ebl, NTHREADS, 0, stream>>>(row, col, rp, cur, dis, ev, e);
  k_wprime<<<dim3(36, NLAYERS), NTHREADS, 0, stream>>>(cw, wTb);
  k_lin0<<<r64, NTHREADS, 0, stream>>>(x, w0, b0, x0f, hbA, n);

  const unsigned short* hin = hbA;
  for (int l = 0; l < NLAYERS; ++l) {
    unsigned short* hout = (l & 1) ? hbA : hbB;
    float beta = logf(0.5f / (float)(l + 1) + 1.0f);
    k_spmm<<<(n + 7) / 8, NTHREADS, 0, stream>>>(hin, x0f, sbuf, rp, ev, n);
    k_gemm<<<r64, NTHREADS, 0, stream>>>(sbuf, wTb + (size_t)l * HID * HID,
                                         hout, 1.0f - beta, beta, n);
    hin = hout;
  }
  k_lin1<<<r64, NTHREADS, 0, stream>>>(hin, w1, b1, (float*)d_out, n);
}

// Round 7
// 694.856 us; speedup vs baseline: 1.3824x; 1.1147x over previous
//
#include <hip/hip_runtime.h>

#define NTHREADS 256
#define HID 96
#define INF 64
#define OUTF 16
#define NLAYERS 16
#define NHW 25088     // packed histogram words (2 nodes/word), fits n<=50176
#define CB 64         // histogram/scatter blocks

typedef __attribute__((ext_vector_type(8))) unsigned short ushort8_t;
typedef __attribute__((ext_vector_type(8))) short short8_t;   // MFMA bf16 A/B frag
typedef __attribute__((ext_vector_type(4))) float f32x4_t;    // MFMA C/D frag

static __device__ __forceinline__ float bf2f(unsigned short u) {
  return __uint_as_float(((unsigned)u) << 16);
}
static __device__ __forceinline__ unsigned short f2bf(float x) {
  unsigned u = __float_as_uint(x);
  return (unsigned short)((u + 0x7FFF + ((u >> 16) & 1)) >> 16);  // RNE
}
static __device__ __forceinline__ unsigned pack2bf(float a, float b) {
  return (unsigned)f2bf(a) | ((unsigned)f2bf(b) << 16);
}

// ---------------- preprocessing ----------------
// LDS-privatized histogram over idx[] (row or col), packed 2 nodes/u32 word.
// Per-block counts <= e/CB (12500) < 65536 -> no carry across halves.
__global__ __launch_bounds__(NTHREADS) void k_hist(
    const int* __restrict__ idx, int e, unsigned* __restrict__ part, int nw) {
  __shared__ unsigned hh[NHW];
  int tid = threadIdx.x;
  for (int i = tid; i < NHW; i += NTHREADS) hh[i] = 0;
  __syncthreads();
  int per = (e + CB - 1) / CB;
  int s = blockIdx.x * per;
  int en = min(e, s + per);
  for (int i = s + tid; i < en; i += NTHREADS) {
    int v = idx[i];
    atomicAdd(&hh[v >> 1], (v & 1) ? 0x10000u : 1u);
  }
  __syncthreads();
  unsigned* dst = part + (size_t)blockIdx.x * NHW;
  for (int i = tid; i < nw; i += NTHREADS) dst[i] = hh[i];
}

// Sum the CB partial histograms -> cnt (rows) and deg (cols), +1 self-loop.
// Also rewrites partR in place as the EXCLUSIVE PREFIX over blocks (packed u16)
// so k_scatter2 can place edges without global atomics.
__global__ void k_hmerge(unsigned* __restrict__ partR,
                         const unsigned* __restrict__ partC,
                         int* __restrict__ cnt, int* __restrict__ deg,
                         int n, int nw) {
  int w = blockIdx.x * NTHREADS + threadIdx.x;
  if (w >= nw) return;
  unsigned rl = 0, rh = 0, cl = 0, ch = 0;
  for (int b = 0; b < CB; ++b) {
    size_t o = (size_t)b * NHW + w;
    unsigned pr = partR[o];
    partR[o] = rl | (rh << 16);          // exclusive prefix (fits u16: deg << 64K)
    rl += pr & 0xFFFFu; rh += pr >> 16;
    unsigned pc = partC[o];
    cl += pc & 0xFFFFu; ch += pc >> 16;
  }
  int i0 = 2 * w, i1 = 2 * w + 1;
  if (i0 < n) { cnt[i0] = 1 + (int)rl; deg[i0] = 1 + (int)cl; }
  if (i1 < n) { cnt[i1] = 1 + (int)rh; deg[i1] = 1 + (int)ch; }
}

__global__ void k_dis(const int* __restrict__ deg, float* __restrict__ dis,
                      float* __restrict__ selfval, int n) {
  int i = blockIdx.x * NTHREADS + threadIdx.x;
  if (i < n) {
    float d = (float)deg[i];
    dis[i] = rsqrtf(d);
    selfval[i] = 1.0f / d;        // dis[i]^2 for the self-loop edge
  }
}

__global__ void k_scan1(const int* __restrict__ cnt, int* __restrict__ rp,
                        int* __restrict__ bsum, int n) {
  __shared__ int sh[NTHREADS];
  int t = threadIdx.x;
  int i = blockIdx.x * NTHREADS + t;
  int v = (i < n) ? cnt[i] : 0;
  sh[t] = v;
  __syncthreads();
  for (int ofs = 1; ofs < NTHREADS; ofs <<= 1) {
    int u = (t >= ofs) ? sh[t - ofs] : 0;
    __syncthreads();
    sh[t] += u;
    __syncthreads();
  }
  if (i < n) rp[i] = sh[t] - v;
  if (t == NTHREADS - 1) bsum[blockIdx.x] = sh[t];
}

__global__ void k_scan2(int* __restrict__ bsum, int nb) {  // nb <= 256
  __shared__ int sh[NTHREADS];
  int t = threadIdx.x;
  int v = (t < nb) ? bsum[t] : 0;
  sh[t] = v;
  __syncthreads();
  for (int ofs = 1; ofs < NTHREADS; ofs <<= 1) {
    int u = (t >= ofs) ? sh[t - ofs] : 0;
    __syncthreads();
    sh[t] += u;
    __syncthreads();
  }
  if (t < nb) bsum[t] = sh[t] - v;
}

__global__ void k_scan3(int* __restrict__ rp, const int* __restrict__ bsum,
                        int n, int etot) {
  int i = blockIdx.x * NTHREADS + threadIdx.x;
  if (i < n) rp[i] += bsum[blockIdx.x];
  if (i == 0) rp[n] = etot;
}

// fill reserved slot 0 of each row with the self-loop edge
__global__ void k_self(const int* __restrict__ rp, const float* __restrict__ sv,
                       int2* __restrict__ ev, int n) {
  int i = blockIdx.x * NTHREADS + threadIdx.x;
  if (i < n) {
    int2 v;
    v.x = i;
    v.y = __float_as_int(sv[i]);
    ev[rp[i]] = v;
  }
}

// Atomic-free-global scatter: block b owns the same edge slice as k_hist block b;
// slot = rp[r] + 1 (self slot) + prefix_over_blocks[b][r] + LDS-local counter.
__global__ __launch_bounds__(NTHREADS) void k_scatter2(
    const int* __restrict__ row, const int* __restrict__ col,
    const int* __restrict__ rp, const unsigned* __restrict__ prefR,
    const float* __restrict__ dis, int2* __restrict__ ev, int e) {
  __shared__ unsigned lcur[NHW];
  int tid = threadIdx.x;
  for (int i = tid; i < NHW; i += NTHREADS) lcur[i] = 0;
  __syncthreads();
  int per = (e + CB - 1) / CB;
  int s = blockIdx.x * per;
  int en = min(e, s + per);
  const unsigned* pref = prefR + (size_t)blockIdx.x * NHW;
  for (int i = s + tid; i < en; i += NTHREADS) {
    int r = row[i], c = col[i];
    unsigned old = atomicAdd(&lcur[r >> 1], (r & 1) ? 0x10000u : 1u);
    unsigned loc = (r & 1) ? (old >> 16) : (old & 0xFFFFu);
    unsigned pw = pref[r >> 1];
    unsigned pb = (r & 1) ? (pw >> 16) : (pw & 0xFFFFu);
    int p = rp[r] + 1 + (int)pb + (int)loc;
    int2 v;
    v.x = c;
    v.y = __float_as_int(dis[r] * dis[c]);
    ev[p] = v;
  }
}

// wT_bf16[l][f][k] = bf16(conv_w[l][k][f])  (transposed for MFMA B-fragments)
__global__ void k_wprime(const float* __restrict__ cw,
                         unsigned short* __restrict__ wTb) {
  int l = blockIdx.y;
  int idx = blockIdx.x * NTHREADS + threadIdx.x;   // 0..9215 = f*96 + k
  int f = idx / HID, k = idx % HID;
  wTb[l * HID * HID + idx] = f2bf(cw[l * HID * HID + k * HID + f]);
}

// ---------------- x0 = h0 = relu(x @ w0^T + b0), stored bf16 ----------------
__global__ __launch_bounds__(NTHREADS) void k_lin0(
    const float* __restrict__ x, const float* __restrict__ w0,
    const float* __restrict__ b0, unsigned short* __restrict__ x0b, int n) {
  __shared__ float wl[INF * HID];   // wl[c][h], stride 96
  __shared__ float xT[INF * 68];    // xT[c][r], padded stride 68
  int tid = threadIdx.x;
#pragma unroll
  for (int i = 0; i < 6; ++i) {     // w0: 96x64 = 1536 float4
    int idx = tid + i * NTHREADS;
    int hrow = idx / 16, q = idx % 16;
    float4 v = *(const float4*)(w0 + hrow * INF + q * 4);
    wl[(q * 4 + 0) * HID + hrow] = v.x;
    wl[(q * 4 + 1) * HID + hrow] = v.y;
    wl[(q * 4 + 2) * HID + hrow] = v.z;
    wl[(q * 4 + 3) * HID + hrow] = v.w;
  }
  int r0 = blockIdx.x * 64;
#pragma unroll
  for (int i = 0; i < 4; ++i) {     // x tile: 64x64 = 1024 float4
    int idx = tid + i * NTHREADS;
    int r = idx / 16, q = idx % 16;
    int gr = r0 + r;
    float4 v = make_float4(0.f, 0.f, 0.f, 0.f);
    if (gr < n) v = *(const float4*)(x + (size_t)gr * INF + q * 4);
    xT[(q * 4 + 0) * 68 + r] = v.x;
    xT[(q * 4 + 1) * 68 + r] = v.y;
    xT[(q * 4 + 2) * 68 + r] = v.z;
    xT[(q * 4 + 3) * 68 + r] = v.w;
  }
  __syncthreads();
  int rg = tid & 15, cg = tid >> 4;
  float acc[4][6];
#pragma unroll
  for (int i = 0; i < 4; ++i)
#pragma unroll
    for (int j = 0; j < 6; ++j) acc[i][j] = 0.f;
#pragma unroll 4
  for (int k = 0; k < INF; ++k) {
    float4 s4 = *(const float4*)(xT + k * 68 + rg * 4);
    const float2* w2 = (const float2*)(wl + k * HID + cg * 6);
    float2 wa = w2[0], wb = w2[1], wc = w2[2];
    float wv[6] = {wa.x, wa.y, wb.x, wb.y, wc.x, wc.y};
    float sv[4] = {s4.x, s4.y, s4.z, s4.w};
#pragma unroll
    for (int i = 0; i < 4; ++i)
#pragma unroll
      for (int j = 0; j < 6; ++j) acc[i][j] = fmaf(sv[i], wv[j], acc[i][j]);
  }
  float bb[6];
#pragma unroll
  for (int j = 0; j < 6; ++j) bb[j] = b0[cg * 6 + j];
#pragma unroll
  for (int i = 0; i < 4; ++i) {
    int gr = r0 + rg * 4 + i;
    if (gr < n) {
      float r_[6];
#pragma unroll
      for (int j = 0; j < 6; ++j) r_[j] = fmaxf(acc[i][j] + bb[j], 0.f);
      unsigned* ob = (unsigned*)(x0b + (size_t)gr * HID + cg * 6);
      ob[0] = pack2bf(r_[0], r_[1]);
      ob[1] = pack2bf(r_[2], r_[3]);
      ob[2] = pack2bf(r_[4], r_[5]);
    }
  }
}

// ------- SpMM + residual: s = 0.9*(A_hat h) + 0.1*x0, all state bf16 ---------
// half-wave per row; 32 lanes = 8 edge-slots x 4 feature-groups (24 feats each).
// Reduction is INTRA-WAVE -> wave_barrier only, no block rendezvous.
__global__ __launch_bounds__(NTHREADS) void k_spmm(
    const unsigned short* __restrict__ hin, const unsigned short* __restrict__ x0,
    unsigned short* __restrict__ sout, const int* __restrict__ rp,
    const int2* __restrict__ ev, int n) {
  __shared__ float red[8][8][100];
  int t = threadIdx.x;
  int hw = t >> 5;            // half-wave id 0..7 (one row each)
  int lane = t & 31;
  int eb = lane >> 2;         // edge slot 0..7
  int fg = lane & 3;          // feature group 0..3 (24 features)
  int r = blockIdx.x * 8 + hw;
  if (r >= n) r = n - 1;      // clamp: duplicate work, benign same-value write
  int e0 = rp[r], e1 = rp[r + 1];   // >= 1 edge always (self-loop)
  float acc[24];
#pragma unroll
  for (int j = 0; j < 24; ++j) acc[j] = 0.f;

  int idx0 = e0 + eb;
  bool ok = idx0 < e1;
  idx0 = ok ? idx0 : e1 - 1;
  int2 cv = ev[idx0];
  for (int base = e0; base < e1; base += 8) {
    int2 cur = cv;
    bool okc = ok;
    int nb = base + 8;
    if (nb < e1) {            // prefetch next batch of edges
      int i2 = nb + eb;
      ok = i2 < e1;
      i2 = ok ? i2 : e1 - 1;
      cv = ev[i2];
    }
    float v = okc ? __int_as_float(cur.y) : 0.f;
    const unsigned short* hc = hin + (size_t)cur.x * HID + fg * 24;
    ushort8_t p0 = *(const ushort8_t*)(hc);
    ushort8_t p1 = *(const ushort8_t*)(hc + 8);
    ushort8_t p2 = *(const ushort8_t*)(hc + 16);
#pragma unroll
    for (int j = 0; j < 8; ++j) acc[j]      = fmaf(v, bf2f(p0[j]), acc[j]);
#pragma unroll
    for (int j = 0; j < 8; ++j) acc[8 + j]  = fmaf(v, bf2f(p1[j]), acc[8 + j]);
#pragma unroll
    for (int j = 0; j < 8; ++j) acc[16 + j] = fmaf(v, bf2f(p2[j]), acc[16 + j]);
  }
  // partial sums -> LDS (consumed only by this same wave)
  float* myr = &red[hw][eb][fg * 24];
#pragma unroll
  for (int j = 0; j < 6; ++j)
    *(float4*)(myr + j * 4) =
        make_float4(acc[j * 4], acc[j * 4 + 1], acc[j * 4 + 2], acc[j * 4 + 3]);
  asm volatile("s_waitcnt lgkmcnt(0)" ::: "memory");
  __builtin_amdgcn_wave_barrier();
  // lanes 0..23 of each half-wave: sum 8 edge-slot copies of 4 features each
  if (lane < 24) {
    float4 tot = *(const float4*)(&red[hw][0][lane * 4]);
#pragma unroll
    for (int b = 1; b < 8; ++b) {
      float4 p = *(const float4*)(&red[hw][b][lane * 4]);
      tot.x += p.x; tot.y += p.y; tot.z += p.z; tot.w += p.w;
    }
    size_t o = (size_t)r * HID + lane * 4;
    const unsigned* xr = (const unsigned*)(x0 + o);
    unsigned xa = xr[0], xb = xr[1];
    float s0 = 0.9f * tot.x + 0.1f * bf2f((unsigned short)(xa & 0xFFFFu));
    float s1 = 0.9f * tot.y + 0.1f * bf2f((unsigned short)(xa >> 16));
    float s2 = 0.9f * tot.z + 0.1f * bf2f((unsigned short)(xb & 0xFFFFu));
    float s3 = 0.9f * tot.w + 0.1f * bf2f((unsigned short)(xb >> 16));
    unsigned* op = (unsigned*)(sout + o);
    op[0] = pack2bf(s0, s1);
    op[1] = pack2bf(s2, s3);
  }
}

// -------- h' = relu((1-b)*s + b*(s @ w)), MFMA bf16, s bf16, 64 rows/block -----
__global__ __launch_bounds__(NTHREADS) void k_gemm(
    const unsigned short* __restrict__ s, const unsigned short* __restrict__ wT,
    unsigned short* __restrict__ hout, float omb, float beta, int n) {
  __shared__ unsigned short sT[64 * 104];   // [r][k] bf16, stride 104 (pad)
  __shared__ unsigned short wl[HID * 104];  // [f][k] bf16, stride 104 (pad)
  int tid = threadIdx.x;
  int r0 = blockIdx.x * 64;
#pragma unroll
  for (int i = 0; i < 3; ++i) {     // s tile: 64x96 bf16 = 768 ushort8
    int idx = tid + i * NTHREADS;
    int r = idx / 12, q = idx % 12;
    int gr = r0 + r;
    ushort8_t v = (ushort8_t)0;
    if (gr < n) v = *(const ushort8_t*)(s + (size_t)gr * HID + q * 8);
    *(ushort8_t*)(sT + r * 104 + q * 8) = v;
  }
#pragma unroll
  for (int i = 0; i < 5; ++i) {     // wT: 96x96 bf16 = 1152 ushort8
    int idx = tid + i * NTHREADS;
    if (idx < 1152) {
      int f = idx / 12, c = (idx % 12) * 8;
      ushort8_t v = *(const ushort8_t*)(wT + f * HID + c);
      *(ushort8_t*)(wl + f * 104 + c) = v;
    }
  }
  __syncthreads();
  int lane = tid & 63, wave = tid >> 6;
  int l15 = lane & 15;      // A-row / B-col / C-col
  int kg = lane >> 4;       // k-group 0..3
  f32x4_t acc[6];
#pragma unroll
  for (int i = 0; i < 6; ++i) acc[i] = (f32x4_t)(0.f);
#pragma unroll
  for (int kt = 0; kt < 3; ++kt) {
    short8_t A = *(const short8_t*)(sT + (wave * 16 + l15) * 104 + kt * 32 + kg * 8);
#pragma unroll
    for (int ft = 0; ft < 6; ++ft) {
      short8_t B = *(const short8_t*)(wl + (ft * 16 + l15) * 104 + kt * 32 + kg * 8);
      acc[ft] = __builtin_amdgcn_mfma_f32_16x16x32_bf16(A, B, acc[ft], 0, 0, 0);
    }
  }
  // epilogue: C layout col = lane&15, row = (lane>>4)*4 + j   [m89-verified]
#pragma unroll
  for (int ft = 0; ft < 6; ++ft) {
    int col = ft * 16 + l15;
#pragma unroll
    for (int j = 0; j < 4; ++j) {
      int rl = wave * 16 + kg * 4 + j;
      int gr = r0 + rl;
      float sv = bf2f(sT[rl * 104 + col]);
      float o = fmaxf(omb * sv + beta * acc[ft][j], 0.f);
      if (gr < n) hout[(size_t)gr * HID + col] = f2bf(o);
    }
  }
}

// ---------------- out = h @ w1^T + b1  (h is bf16) ----------------
__global__ __launch_bounds__(NTHREADS) void k_lin1(
    const unsigned short* __restrict__ h, const float* __restrict__ w1,
    const float* __restrict__ b1, float* __restrict__ out, int n) {
  __shared__ float hT[HID * 68];    // [k][r]
  __shared__ float w1l[HID * OUTF]; // [k][o]
  int tid = threadIdx.x;
#pragma unroll
  for (int i = 0; i < 6; ++i) {     // w1: 16x96 = 1536 floats
    int idx = tid + i * NTHREADS;
    int o = idx / HID, k = idx % HID;
    w1l[k * OUTF + o] = w1[idx];
  }
  int r0 = blockIdx.x * 64;
#pragma unroll
  for (int i = 0; i < 3; ++i) {     // h tile: 64x96 bf16 = 768 ushort8
    int idx = tid + i * NTHREADS;
    int r = idx / 12, q = idx % 12;
    int gr = r0 + r;
    ushort8_t v = (ushort8_t)0;
    if (gr < n) v = *(const ushort8_t*)(h + (size_t)gr * HID + q * 8);
#pragma unroll
    for (int j = 0; j < 8; ++j) hT[(q * 8 + j) * 68 + r] = bf2f(v[j]);
  }
  __syncthreads();
  int r = tid & 63, og = tid >> 6;
  float acc[4] = {0.f, 0.f, 0.f, 0.f};
#pragma unroll 4
  for (int k = 0; k < HID; ++k) {
    float s = hT[k * 68 + r];
    float4 w4 = *(const float4*)(w1l + k * OUTF + og * 4);
    acc[0] = fmaf(s, w4.x, acc[0]);
    acc[1] = fmaf(s, w4.y, acc[1]);
    acc[2] = fmaf(s, w4.z, acc[2]);
    acc[3] = fmaf(s, w4.w, acc[3]);
  }
  int gr = r0 + r;
  if (gr < n) {
    float* op = out + (size_t)gr * OUTF + og * 4;
#pragma unroll
    for (int j = 0; j < 4; ++j) op[j] = acc[j] + b1[og * 4 + j];
  }
}

extern "C" void kernel_launch(void* const* d_in, const int* in_sizes, int n_in,
                              void* d_out, int out_size, void* d_ws, size_t ws_size,
                              hipStream_t stream) {
  const float* x  = (const float*)d_in[0];
  const int*   ei = (const int*)d_in[1];     // [2][E]: rows then cols
  const float* w0 = (const float*)d_in[2];
  const float* b0 = (const float*)d_in[3];
  const float* w1 = (const float*)d_in[4];
  const float* b1 = (const float*)d_in[5];
  const float* cw = (const float*)d_in[6];
  int n = in_sizes[0] / INF;    // 50000
  int e = in_sizes[1] / 2;      // 800000
  const int* row = ei;
  const int* col = ei + e;

  char* ws = (char*)d_ws;
  size_t off = 0;
  auto alloc = [&](size_t bytes) -> void* {
    void* p = (void*)(ws + off);
    off += (bytes + 255) & ~(size_t)255;
    return p;
  };
  unsigned short* x0b = (unsigned short*)alloc((size_t)n * HID * 2);
  unsigned short* sb  = (unsigned short*)alloc((size_t)n * HID * 2);
  unsigned short* hbA = (unsigned short*)alloc((size_t)n * HID * 2);
  unsigned short* hbB = (unsigned short*)alloc((size_t)n * HID * 2);
  unsigned short* wTb = (unsigned short*)alloc((size_t)NLAYERS * HID * HID * 2);
  int*   deg  = (int*)alloc((size_t)n * 4);
  float* dis  = (float*)alloc((size_t)n * 4);
  float* sv   = (float*)alloc((size_t)n * 4);
  int*   cnt  = (int*)alloc((size_t)n * 4);
  int*   rp   = (int*)alloc((size_t)(n + 1) * 4);
  int2*  ev   = (int2*)alloc((size_t)(e + n) * 8);  // + self-loop slots
  int*   bsum = (int*)alloc(1024 * 4);
  unsigned* partR = (unsigned*)alloc((size_t)CB * NHW * 4);
  unsigned* partC = (unsigned*)alloc((size_t)CB * NHW * 4);
  int nw = (n + 1) / 2;         // packed words (<= NHW)
  (void)ws_size; (void)n_in; (void)out_size;

  int nb  = (n + NTHREADS - 1) / NTHREADS;   // 196
  int r64 = (n + 63) / 64;                   // 782

  k_hist<<<CB, NTHREADS, 0, stream>>>(row, e, partR, nw);
  k_hist<<<CB, NTHREADS, 0, stream>>>(col, e, partC, nw);
  k_hmerge<<<(nw + NTHREADS - 1) / NTHREADS, NTHREADS, 0, stream>>>(
      partR, partC, cnt, deg, n, nw);
  k_dis<<<nb, NTHREADS, 0, stream>>>(deg, dis, sv, n);
  k_scan1<<<nb, NTHREADS, 0, stream>>>(cnt, rp, bsum, n);
  k_scan2<<<1, NTHREADS, 0, stream>>>(bsum, nb);
  k_scan3<<<nb, NTHREADS, 0, stream>>>(rp, bsum, n, e + n);
  k_self<<<nb, NTHREADS, 0, stream>>>(rp, sv, ev, n);
  k_scatter2<<<CB, NTHREADS, 0, stream>>>(row, col, rp, partR, dis, ev, e);
  k_wprime<<<dim3(36, NLAYERS), NTHREADS, 0, stream>>>(cw, wTb);
  k_lin0<<<r64, NTHREADS, 0, stream>>>(x, w0, b0, x0b, n);

  const unsigned short* hin = x0b;
  for (int l = 0; l < NLAYERS; ++l) {
    unsigned short* hout = (l & 1) ? hbB : hbA;
    float beta = logf(0.5f / (float)(l + 1) + 1.0f);
    k_spmm<<<(n + 7) / 8, NTHREADS, 0, stream>>>(hin, x0b, sb, rp, ev, n);
    k_gemm<<<r64, NTHREADS, 0, stream>>>(sb, wTb + (size_t)l * HID * HID,
                                         hout, 1.0f - beta, beta, n);
    hin = hout;
  }
  k_lin1<<<r64, NTHREADS, 0, stream>>>(hin, w1, b1, (float*)d_out, n);
}

// Round 8
// 646.602 us; speedup vs baseline: 1.4855x; 1.0746x over previous
//
#include <hip/hip_runtime.h>

#define NTHREADS 256
#define HID 96
#define INF 64
#define OUTF 16
#define NLAYERS 16
#define NHW 25088     // packed histogram words (2 nodes/word), fits n<=50176
#define CB 128        // histogram/scatter blocks (per-block edges 6250 < 65536)

typedef __attribute__((ext_vector_type(8))) unsigned short ushort8_t;
typedef __attribute__((ext_vector_type(8))) short short8_t;   // MFMA bf16 A/B frag
typedef __attribute__((ext_vector_type(4))) float f32x4_t;    // MFMA C/D frag

static __device__ __forceinline__ float bf2f(unsigned short u) {
  return __uint_as_float(((unsigned)u) << 16);
}
static __device__ __forceinline__ unsigned short f2bf(float x) {
  unsigned u = __float_as_uint(x);
  return (unsigned short)((u + 0x7FFF + ((u >> 16) & 1)) >> 16);  // RNE
}
static __device__ __forceinline__ unsigned pack2bf(float a, float b) {
  return (unsigned)f2bf(a) | ((unsigned)f2bf(b) << 16);
}

// ---------------- preprocessing ----------------
// LDS-privatized histogram over idx[] (row or col), packed 2 nodes/u32 word.
__global__ __launch_bounds__(NTHREADS) void k_hist(
    const int* __restrict__ idx, int e, unsigned* __restrict__ part, int nw) {
  __shared__ unsigned hh[NHW];
  int tid = threadIdx.x;
  for (int i = tid; i < NHW; i += NTHREADS) hh[i] = 0;
  __syncthreads();
  int per = (e + CB - 1) / CB;
  int s = blockIdx.x * per;
  int en = min(e, s + per);
  for (int i = s + tid; i < en; i += NTHREADS) {
    int v = idx[i];
    atomicAdd(&hh[v >> 1], (v & 1) ? 0x10000u : 1u);
  }
  __syncthreads();
  unsigned* dst = part + (size_t)blockIdx.x * NHW;
  for (int i = tid; i < nw; i += NTHREADS) dst[i] = hh[i];
}

// Sum the CB partial histograms -> cnt (rows) and deg (cols), +1 self-loop.
// Also rewrites partR in place as the EXCLUSIVE PREFIX over blocks (packed u16).
__global__ void k_hmerge(unsigned* __restrict__ partR,
                         const unsigned* __restrict__ partC,
                         int* __restrict__ cnt, int* __restrict__ deg,
                         int n, int nw) {
  int w = blockIdx.x * NTHREADS + threadIdx.x;
  if (w >= nw) return;
  unsigned rl = 0, rh = 0, cl = 0, ch = 0;
#pragma unroll 4
  for (int b = 0; b < CB; ++b) {
    size_t o = (size_t)b * NHW + w;
    unsigned pr = partR[o];
    partR[o] = rl | (rh << 16);          // exclusive prefix (fits u16)
    rl += pr & 0xFFFFu; rh += pr >> 16;
    unsigned pc = partC[o];
    cl += pc & 0xFFFFu; ch += pc >> 16;
  }
  int i0 = 2 * w, i1 = 2 * w + 1;
  if (i0 < n) { cnt[i0] = 1 + (int)rl; deg[i0] = 1 + (int)cl; }
  if (i1 < n) { cnt[i1] = 1 + (int)rh; deg[i1] = 1 + (int)ch; }
}

__global__ void k_dis(const int* __restrict__ deg, float* __restrict__ dis,
                      float* __restrict__ selfval, int n) {
  int i = blockIdx.x * NTHREADS + threadIdx.x;
  if (i < n) {
    float d = (float)deg[i];
    dis[i] = rsqrtf(d);
    selfval[i] = 1.0f / d;        // dis[i]^2 for the self-loop edge
  }
}

__global__ void k_scan1(const int* __restrict__ cnt, int* __restrict__ rp,
                        int* __restrict__ bsum, int n) {
  __shared__ int sh[NTHREADS];
  int t = threadIdx.x;
  int i = blockIdx.x * NTHREADS + t;
  int v = (i < n) ? cnt[i] : 0;
  sh[t] = v;
  __syncthreads();
  for (int ofs = 1; ofs < NTHREADS; ofs <<= 1) {
    int u = (t >= ofs) ? sh[t - ofs] : 0;
    __syncthreads();
    sh[t] += u;
    __syncthreads();
  }
  if (i < n) rp[i] = sh[t] - v;
  if (t == NTHREADS - 1) bsum[blockIdx.x] = sh[t];
}

__global__ void k_scan2(int* __restrict__ bsum, int nb) {  // nb <= 256
  __shared__ int sh[NTHREADS];
  int t = threadIdx.x;
  int v = (t < nb) ? bsum[t] : 0;
  sh[t] = v;
  __syncthreads();
  for (int ofs = 1; ofs < NTHREADS; ofs <<= 1) {
    int u = (t >= ofs) ? sh[t - ofs] : 0;
    __syncthreads();
    sh[t] += u;
    __syncthreads();
  }
  if (t < nb) bsum[t] = sh[t] - v;
}

__global__ void k_scan3(int* __restrict__ rp, const int* __restrict__ bsum,
                        int n, int etot) {
  int i = blockIdx.x * NTHREADS + threadIdx.x;
  if (i < n) rp[i] += bsum[blockIdx.x];
  if (i == 0) rp[n] = etot;
}

// fill reserved slot 0 of each row with the self-loop edge
__global__ void k_self(const int* __restrict__ rp, const float* __restrict__ sv,
                       int2* __restrict__ ev, int n) {
  int i = blockIdx.x * NTHREADS + threadIdx.x;
  if (i < n) {
    int2 v;
    v.x = i;
    v.y = __float_as_int(sv[i]);
    ev[rp[i]] = v;
  }
}

// Atomic-free-global scatter: block b owns the same edge slice as k_hist block b;
// slot = rp[r] + 1 (self slot) + prefix_over_blocks[b][r] + LDS-local counter.
__global__ __launch_bounds__(NTHREADS) void k_scatter2(
    const int* __restrict__ row, const int* __restrict__ col,
    const int* __restrict__ rp, const unsigned* __restrict__ prefR,
    const float* __restrict__ dis, int2* __restrict__ ev, int e) {
  __shared__ unsigned lcur[NHW];
  int tid = threadIdx.x;
  for (int i = tid; i < NHW; i += NTHREADS) lcur[i] = 0;
  __syncthreads();
  int per = (e + CB - 1) / CB;
  int s = blockIdx.x * per;
  int en = min(e, s + per);
  const unsigned* pref = prefR + (size_t)blockIdx.x * NHW;
  for (int i = s + tid; i < en; i += NTHREADS) {
    int r = row[i], c = col[i];
    unsigned old = atomicAdd(&lcur[r >> 1], (r & 1) ? 0x10000u : 1u);
    unsigned loc = (r & 1) ? (old >> 16) : (old & 0xFFFFu);
    unsigned pw = pref[r >> 1];
    unsigned pb = (r & 1) ? (pw >> 16) : (pw & 0xFFFFu);
    int p = rp[r] + 1 + (int)pb + (int)loc;
    int2 v;
    v.x = c;
    v.y = __float_as_int(dis[r] * dis[c]);
    ev[p] = v;
  }
}

// wT_bf16[l][f][k] = bf16(conv_w[l][k][f])  (transposed for MFMA B-fragments)
__global__ void k_wprime(const float* __restrict__ cw,
                         unsigned short* __restrict__ wTb) {
  int l = blockIdx.y;
  int idx = blockIdx.x * NTHREADS + threadIdx.x;   // 0..9215 = f*96 + k
  int f = idx / HID, k = idx % HID;
  wTb[l * HID * HID + idx] = f2bf(cw[l * HID * HID + k * HID + f]);
}

// ---------------- x0 = h0 = relu(x @ w0^T + b0), stored bf16 ----------------
__global__ __launch_bounds__(NTHREADS) void k_lin0(
    const float* __restrict__ x, const float* __restrict__ w0,
    const float* __restrict__ b0, unsigned short* __restrict__ x0b, int n) {
  __shared__ float wl[INF * HID];   // wl[c][h], stride 96
  __shared__ float xT[INF * 68];    // xT[c][r], padded stride 68
  int tid = threadIdx.x;
#pragma unroll
  for (int i = 0; i < 6; ++i) {     // w0: 96x64 = 1536 float4
    int idx = tid + i * NTHREADS;
    int hrow = idx / 16, q = idx % 16;
    float4 v = *(const float4*)(w0 + hrow * INF + q * 4);
    wl[(q * 4 + 0) * HID + hrow] = v.x;
    wl[(q * 4 + 1) * HID + hrow] = v.y;
    wl[(q * 4 + 2) * HID + hrow] = v.z;
    wl[(q * 4 + 3) * HID + hrow] = v.w;
  }
  int r0 = blockIdx.x * 64;
#pragma unroll
  for (int i = 0; i < 4; ++i) {     // x tile: 64x64 = 1024 float4
    int idx = tid + i * NTHREADS;
    int r = idx / 16, q = idx % 16;
    int gr = r0 + r;
    float4 v = make_float4(0.f, 0.f, 0.f, 0.f);
    if (gr < n) v = *(const float4*)(x + (size_t)gr * INF + q * 4);
    xT[(q * 4 + 0) * 68 + r] = v.x;
    xT[(q * 4 + 1) * 68 + r] = v.y;
    xT[(q * 4 + 2) * 68 + r] = v.z;
    xT[(q * 4 + 3) * 68 + r] = v.w;
  }
  __syncthreads();
  int rg = tid & 15, cg = tid >> 4;
  float acc[4][6];
#pragma unroll
  for (int i = 0; i < 4; ++i)
#pragma unroll
    for (int j = 0; j < 6; ++j) acc[i][j] = 0.f;
#pragma unroll 4
  for (int k = 0; k < INF; ++k) {
    float4 s4 = *(const float4*)(xT + k * 68 + rg * 4);
    const float2* w2 = (const float2*)(wl + k * HID + cg * 6);
    float2 wa = w2[0], wb = w2[1], wc = w2[2];
    float wv[6] = {wa.x, wa.y, wb.x, wb.y, wc.x, wc.y};
    float sv[4] = {s4.x, s4.y, s4.z, s4.w};
#pragma unroll
    for (int i = 0; i < 4; ++i)
#pragma unroll
      for (int j = 0; j < 6; ++j) acc[i][j] = fmaf(sv[i], wv[j], acc[i][j]);
  }
  float bb[6];
#pragma unroll
  for (int j = 0; j < 6; ++j) bb[j] = b0[cg * 6 + j];
#pragma unroll
  for (int i = 0; i < 4; ++i) {
    int gr = r0 + rg * 4 + i;
    if (gr < n) {
      float r_[6];
#pragma unroll
      for (int j = 0; j < 6; ++j) r_[j] = fmaxf(acc[i][j] + bb[j], 0.f);
      unsigned* ob = (unsigned*)(x0b + (size_t)gr * HID + cg * 6);
      ob[0] = pack2bf(r_[0], r_[1]);
      ob[1] = pack2bf(r_[2], r_[3]);
      ob[2] = pack2bf(r_[4], r_[5]);
    }
  }
}

// ------- fused layer: h' = relu((1-b)*s + b*(s @ w)), s = 0.9*A_hat h + 0.1*x0 --
// Phase 1 (spmm): 8 sub-iterations; half-wave hw handles row r0+sub*8+hw via
// 8-edge-slot x 4-feature-group lanes; wave-local LDS reduce; s packed bf16
// straight into the sT tile (no global round-trip).
// Phase 2 (gemm): MFMA on sT x wl. red (phase-1) and wl (phase-2) share LDS.
__global__ __launch_bounds__(NTHREADS) void k_layer(
    const unsigned short* __restrict__ hin, const unsigned short* __restrict__ x0,
    const int* __restrict__ rp, const int2* __restrict__ ev,
    const unsigned short* __restrict__ wT, unsigned short* __restrict__ hout,
    float omb, float beta, int n) {
  __shared__ unsigned char pool[38912] __attribute__((aligned(16)));
  float* red = (float*)pool;                            // [8][8][100] (25600 B)
  unsigned short* wl = (unsigned short*)pool;           // [96][104]   (19968 B)
  unsigned short* sT = (unsigned short*)(pool + 25600); // [64][104]   (13312 B)
  int tid = threadIdx.x;
  int hw = tid >> 5, lane = tid & 31;
  int eb = lane >> 2, fg = lane & 3;
  int r0 = blockIdx.x * 64;

  // ---- phase 1: SpMM + residual into sT ----
  for (int sub = 0; sub < 8; ++sub) {
    int rl = sub * 8 + hw;
    int r = r0 + rl;
    if (r >= n) r = n - 1;          // duplicate work; store guarded in phase 2
    int e0 = rp[r], e1 = rp[r + 1]; // >= 1 edge (self-loop)
    float acc[24];
#pragma unroll
    for (int j = 0; j < 24; ++j) acc[j] = 0.f;
    int idx0 = e0 + eb;
    bool ok = idx0 < e1;
    idx0 = ok ? idx0 : e1 - 1;
    int2 cv = ev[idx0];
    for (int base = e0; base < e1; base += 8) {
      int2 cur = cv;
      bool okc = ok;
      int nb = base + 8;
      if (nb < e1) {                // prefetch next batch
        int i2 = nb + eb;
        ok = i2 < e1;
        i2 = ok ? i2 : e1 - 1;
        cv = ev[i2];
      }
      float v = okc ? __int_as_float(cur.y) : 0.f;
      const unsigned short* hc = hin + (size_t)cur.x * HID + fg * 24;
      ushort8_t p0 = *(const ushort8_t*)(hc);
      ushort8_t p1 = *(const ushort8_t*)(hc + 8);
      ushort8_t p2 = *(const ushort8_t*)(hc + 16);
#pragma unroll
      for (int j = 0; j < 8; ++j) acc[j]      = fmaf(v, bf2f(p0[j]), acc[j]);
#pragma unroll
      for (int j = 0; j < 8; ++j) acc[8 + j]  = fmaf(v, bf2f(p1[j]), acc[8 + j]);
#pragma unroll
      for (int j = 0; j < 8; ++j) acc[16 + j] = fmaf(v, bf2f(p2[j]), acc[16 + j]);
    }
    float* myr = red + (hw * 8 + eb) * 100 + fg * 24;
#pragma unroll
    for (int j = 0; j < 6; ++j)
      *(float4*)(myr + j * 4) =
          make_float4(acc[j * 4], acc[j * 4 + 1], acc[j * 4 + 2], acc[j * 4 + 3]);
    asm volatile("s_waitcnt lgkmcnt(0)" ::: "memory");
    __builtin_amdgcn_wave_barrier();
    if (lane < 24) {
      const float* base = red + hw * 800 + lane * 4;
      float4 tot = *(const float4*)(base);
#pragma unroll
      for (int b = 1; b < 8; ++b) {
        float4 p = *(const float4*)(base + b * 100);
        tot.x += p.x; tot.y += p.y; tot.z += p.z; tot.w += p.w;
      }
      const unsigned* xr = (const unsigned*)(x0 + (size_t)r * HID + lane * 4);
      unsigned xa = xr[0], xb = xr[1];
      float s0 = 0.9f * tot.x + 0.1f * bf2f((unsigned short)(xa & 0xFFFFu));
      float s1 = 0.9f * tot.y + 0.1f * bf2f((unsigned short)(xa >> 16));
      float s2 = 0.9f * tot.z + 0.1f * bf2f((unsigned short)(xb & 0xFFFFu));
      float s3 = 0.9f * tot.w + 0.1f * bf2f((unsigned short)(xb >> 16));
      unsigned* op = (unsigned*)(sT + rl * 104 + lane * 4);
      op[0] = pack2bf(s0, s1);
      op[1] = pack2bf(s2, s3);
    }
    asm volatile("" ::: "memory");
    __builtin_amdgcn_wave_barrier();  // red reads done before next sub's writes
  }
  __syncthreads();
  // ---- stage wl (overwrites red region) ----
#pragma unroll
  for (int i = 0; i < 5; ++i) {       // wT: 96x96 bf16 = 1152 ushort8
    int idx = tid + i * NTHREADS;
    if (idx < 1152) {
      int f = idx / 12, c = (idx % 12) * 8;
      *(ushort8_t*)(wl + f * 104 + c) = *(const ushort8_t*)(wT + f * HID + c);
    }
  }
  __syncthreads();
  // ---- phase 2: MFMA gemm on sT x wl ----
  int lane64 = tid & 63, wave = tid >> 6;
  int l15 = lane64 & 15;    // A-row / B-col / C-col
  int kg = lane64 >> 4;     // k-group 0..3
  f32x4_t acc2[6];
#pragma unroll
  for (int i = 0; i < 6; ++i) acc2[i] = (f32x4_t)(0.f);
#pragma unroll
  for (int kt = 0; kt < 3; ++kt) {
    short8_t A = *(const short8_t*)(sT + (wave * 16 + l15) * 104 + kt * 32 + kg * 8);
#pragma unroll
    for (int ft = 0; ft < 6; ++ft) {
      short8_t B = *(const short8_t*)(wl + (ft * 16 + l15) * 104 + kt * 32 + kg * 8);
      acc2[ft] = __builtin_amdgcn_mfma_f32_16x16x32_bf16(A, B, acc2[ft], 0, 0, 0);
    }
  }
  // epilogue: C layout col = lane&15, row = (lane>>4)*4 + j   [m89-verified]
#pragma unroll
  for (int ft = 0; ft < 6; ++ft) {
    int col = ft * 16 + l15;
#pragma unroll
    for (int j = 0; j < 4; ++j) {
      int rl = wave * 16 + kg * 4 + j;
      int gr = r0 + rl;
      float sv = bf2f(sT[rl * 104 + col]);
      float o = fmaxf(omb * sv + beta * acc2[ft][j], 0.f);
      if (gr < n) hout[(size_t)gr * HID + col] = f2bf(o);
    }
  }
}

// ---------------- out = h @ w1^T + b1  (h is bf16) ----------------
__global__ __launch_bounds__(NTHREADS) void k_lin1(
    const unsigned short* __restrict__ h, const float* __restrict__ w1,
    const float* __restrict__ b1, float* __restrict__ out, int n) {
  __shared__ float hT[HID * 68];    // [k][r]
  __shared__ float w1l[HID * OUTF]; // [k][o]
  int tid = threadIdx.x;
#pragma unroll
  for (int i = 0; i < 6; ++i) {     // w1: 16x96 = 1536 floats
    int idx = tid + i * NTHREADS;
    int o = idx / HID, k = idx % HID;
    w1l[k * OUTF + o] = w1[idx];
  }
  int r0 = blockIdx.x * 64;
#pragma unroll
  for (int i = 0; i < 3; ++i) {     // h tile: 64x96 bf16 = 768 ushort8
    int idx = tid + i * NTHREADS;
    int r = idx / 12, q = idx % 12;
    int gr = r0 + r;
    ushort8_t v = (ushort8_t)0;
    if (gr < n) v = *(const ushort8_t*)(h + (size_t)gr * HID + q * 8);
#pragma unroll
    for (int j = 0; j < 8; ++j) hT[(q * 8 + j) * 68 + r] = bf2f(v[j]);
  }
  __syncthreads();
  int r = tid & 63, og = tid >> 6;
  float acc[4] = {0.f, 0.f, 0.f, 0.f};
#pragma unroll 4
  for (int k = 0; k < HID; ++k) {
    float s = hT[k * 68 + r];
    float4 w4 = *(const float4*)(w1l + k * OUTF + og * 4);
    acc[0] = fmaf(s, w4.x, acc[0]);
    acc[1] = fmaf(s, w4.y, acc[1]);
    acc[2] = fmaf(s, w4.z, acc[2]);
    acc[3] = fmaf(s, w4.w, acc[3]);
  }
  int gr = r0 + r;
  if (gr < n) {
    float* op = out + (size_t)gr * OUTF + og * 4;
#pragma unroll
    for (int j = 0; j < 4; ++j) op[j] = acc[j] + b1[og * 4 + j];
  }
}

extern "C" void kernel_launch(void* const* d_in, const int* in_sizes, int n_in,
                              void* d_out, int out_size, void* d_ws, size_t ws_size,
                              hipStream_t stream) {
  const float* x  = (const float*)d_in[0];
  const int*   ei = (const int*)d_in[1];     // [2][E]: rows then cols
  const float* w0 = (const float*)d_in[2];
  const float* b0 = (const float*)d_in[3];
  const float* w1 = (const float*)d_in[4];
  const float* b1 = (const float*)d_in[5];
  const float* cw = (const float*)d_in[6];
  int n = in_sizes[0] / INF;    // 50000
  int e = in_sizes[1] / 2;      // 800000
  const int* row = ei;
  const int* col = ei + e;

  char* ws = (char*)d_ws;
  size_t off = 0;
  auto alloc = [&](size_t bytes) -> void* {
    void* p = (void*)(ws + off);
    off += (bytes + 255) & ~(size_t)255;
    return p;
  };
  unsigned short* x0b = (unsigned short*)alloc((size_t)n * HID * 2);
  unsigned short* hbA = (unsigned short*)alloc((size_t)n * HID * 2);
  unsigned short* hbB = (unsigned short*)alloc((size_t)n * HID * 2);
  unsigned short* wTb = (unsigned short*)alloc((size_t)NLAYERS * HID * HID * 2);
  int*   deg  = (int*)alloc((size_t)n * 4);
  float* dis  = (float*)alloc((size_t)n * 4);
  float* sv   = (float*)alloc((size_t)n * 4);
  int*   cnt  = (int*)alloc((size_t)n * 4);
  int*   rp   = (int*)alloc((size_t)(n + 1) * 4);
  int2*  ev   = (int2*)alloc((size_t)(e + n) * 8);  // + self-loop slots
  int*   bsum = (int*)alloc(1024 * 4);
  // partial histograms alias x0b/hbA/hbB (25.7 MB <= 28.8 MB; those buffers are
  // first written by k_lin0 / k_layer, which run after k_scatter2)
  unsigned* partR = (unsigned*)x0b;
  unsigned* partC = partR + (size_t)CB * NHW;
  int nw = (n + 1) / 2;         // packed words (<= NHW)
  (void)ws_size; (void)n_in; (void)out_size;

  int nb  = (n + NTHREADS - 1) / NTHREADS;   // 196
  int r64 = (n + 63) / 64;                   // 782

  k_hist<<<CB, NTHREADS, 0, stream>>>(row, e, partR, nw);
  k_hist<<<CB, NTHREADS, 0, stream>>>(col, e, partC, nw);
  k_hmerge<<<(nw + NTHREADS - 1) / NTHREADS, NTHREADS, 0, stream>>>(
      partR, partC, cnt, deg, n, nw);
  k_dis<<<nb, NTHREADS, 0, stream>>>(deg, dis, sv, n);
  k_scan1<<<nb, NTHREADS, 0, stream>>>(cnt, rp, bsum, n);
  k_scan2<<<1, NTHREADS, 0, stream>>>(bsum, nb);
  k_scan3<<<nb, NTHREADS, 0, stream>>>(rp, bsum, n, e + n);
  k_self<<<nb, NTHREADS, 0, stream>>>(rp, sv, ev, n);
  k_scatter2<<<CB, NTHREADS, 0, stream>>>(row, col, rp, partR, dis, ev, e);
  k_wprime<<<dim3(36, NLAYERS), NTHREADS, 0, stream>>>(cw, wTb);
  k_lin0<<<r64, NTHREADS, 0, stream>>>(x, w0, b0, x0b, n);

  const unsigned short* hin = x0b;
  for (int l = 0; l < NLAYERS; ++l) {
    unsigned short* hout = (l & 1) ? hbB : hbA;
    float beta = logf(0.5f / (float)(l + 1) + 1.0f);
    k_layer<<<r64, NTHREADS, 0, stream>>>(hin, x0b, rp, ev,
                                          wTb + (size_t)l * HID * HID, hout,
                                          1.0f - beta, beta, n);
    hin = hout;
  }
  k_lin1<<<r64, NTHREADS, 0, stream>>>(hin, w1, b1, (float*)d_out, n);
}